// Round 5
// baseline (6232.412 us; speedup 1.0000x reference)
//
#include <hip/hip_runtime.h>

// Sizes (compile-time): B=4, C=512, H=W=64, S=4096, CI=64.  All fp32.
#define EPS_ 1e-5f

// ---------------- weight packing: OIHW [512,512,3,3] -> [9][512][512] ----------------
__global__ void pack_w_kernel(const float* __restrict__ w, float* __restrict__ wp) {
    int gid = blockIdx.x * 256 + threadIdx.x;           // 9*512*512 = 2359296 total
    if (gid >= 9 * 512 * 512) return;
    int tap = gid >> 18;            // / 262144
    int rem = gid & 262143;
    int o = rem >> 9, c = rem & 511;
    wp[gid] = w[(o * 512 + c) * 9 + tap];
}

// ---------------- conv3x3 (as 9 shifted GEMMs) + BN + ReLU ----------------
// X: [B,512,4096] fp32. WP: [9,512,512].
// mode 0: Y = result        mode 2: Y = result + Y (in-place accumulate)
__global__ void __launch_bounds__(256) conv_bnrelu_kernel(
        const float* __restrict__ X,
        const float* __restrict__ WP,
        const float* __restrict__ gg, const float* __restrict__ bb,
        const float* __restrict__ mn, const float* __restrict__ vr,
        float* __restrict__ Y,
        int mode) {
    __shared__ float As[16][68];
    __shared__ float Bs[16][68];
    const int n  = blockIdx.z;
    const int m0 = blockIdx.y * 64;
    const int s0 = blockIdx.x * 64;
    const int tid = threadIdx.x;
    const float* Xn = X + (size_t)n * 512 * 4096;

    float acc[4][4];
#pragma unroll
    for (int i = 0; i < 4; ++i)
#pragma unroll
        for (int j = 0; j < 4; ++j) acc[i][j] = 0.f;

    const int tm = tid >> 4, tn = tid & 15;
    const int la_m = tid >> 2, la_kq = (tid & 3) * 4;   // A-tile load mapping
    const int lb_col = tid & 63, lb_kr = tid >> 6;      // B-tile load mapping
    const int s_col = s0 + lb_col;
    const int yy = s_col >> 6, xx = s_col & 63;

    for (int tap = 0; tap < 9; ++tap) {
        const int dy = tap / 3 - 1, dx = tap % 3 - 1;
        const bool valid = ((unsigned)(yy + dy) < 64u) && ((unsigned)(xx + dx) < 64u);
        const int shift = dy * 64 + dx;
        const float* Wt = WP + (size_t)tap * 512 * 512 + (size_t)(m0 + la_m) * 512 + la_kq;

        for (int k0 = 0; k0 < 512; k0 += 16) {
            float4 av = *(const float4*)(Wt + k0);
            As[la_kq + 0][la_m] = av.x;
            As[la_kq + 1][la_m] = av.y;
            As[la_kq + 2][la_m] = av.z;
            As[la_kq + 3][la_m] = av.w;
#pragma unroll
            for (int j = 0; j < 4; ++j) {
                int k = lb_kr * 4 + j;
                Bs[k][lb_col] = valid ? Xn[(size_t)(k0 + k) * 4096 + (s_col + shift)] : 0.f;
            }
            __syncthreads();
#pragma unroll
            for (int k = 0; k < 16; ++k) {
                float4 a4 = *(const float4*)&As[k][tm * 4];
                float4 b4 = *(const float4*)&Bs[k][tn * 4];
                float a[4] = {a4.x, a4.y, a4.z, a4.w};
                float b[4] = {b4.x, b4.y, b4.z, b4.w};
#pragma unroll
                for (int i = 0; i < 4; ++i)
#pragma unroll
                    for (int j = 0; j < 4; ++j) acc[i][j] = fmaf(a[i], b[j], acc[i][j]);
            }
            __syncthreads();
        }
    }

#pragma unroll
    for (int i = 0; i < 4; ++i) {
        const int c = m0 + tm * 4 + i;
        const float scale = gg[c] * rsqrtf(vr[c] + EPS_);
        const float bnb = bb[c] - mn[c] * scale;
#pragma unroll
        for (int j = 0; j < 4; ++j) {
            const int s = s0 + tn * 4 + j;
            const float val = fmaxf(acc[i][j] * scale + bnb, 0.f);
            const size_t idx = ((size_t)n * 512 + c) * 4096 + s;
            if (mode == 0) Y[idx] = val;
            else           Y[idx] = val + Y[idx];
        }
    }
}

// ---------------- generic 64x64x16 tiled fp32 GEMM ----------------
// TA=0: A[m,k] (row-major). TA=1: A[k,m].  TB=0: B[k,n]. TB=1: B[n,k].
// EPI=0: C = acc (+bias[m]).  EPI=1: C = scalar*acc + C (read-modify-write).
template <int TA, int TB, int EPI>
__global__ void __launch_bounds__(256) gemm_kernel(
                 const float* __restrict__ A, int lda, long sA,
                 const float* __restrict__ B, int ldb, long sB,
                 float* __restrict__ C, int ldc, long sC,
                 int K, const float* __restrict__ bias,
                 const float* __restrict__ scalar_p) {
    __shared__ float As[16][68];
    __shared__ float Bs[16][68];
    const float* Ab = A + (size_t)blockIdx.z * sA;
    const float* Bb = B + (size_t)blockIdx.z * sB;
    float* Cb = C + (size_t)blockIdx.z * sC;
    const int m0 = blockIdx.y * 64, n0 = blockIdx.x * 64;
    const int tid = threadIdx.x;
    const int tm = tid >> 4, tn = tid & 15;

    float acc[4][4];
#pragma unroll
    for (int i = 0; i < 4; ++i)
#pragma unroll
        for (int j = 0; j < 4; ++j) acc[i][j] = 0.f;

    for (int k0 = 0; k0 < K; k0 += 16) {
        if (TA == 0) {
            int m = tid >> 2, kq = (tid & 3) * 4;
            float4 v = *(const float4*)(Ab + (size_t)(m0 + m) * lda + k0 + kq);
            As[kq + 0][m] = v.x; As[kq + 1][m] = v.y; As[kq + 2][m] = v.z; As[kq + 3][m] = v.w;
        } else {
            int k = tid >> 4, mq = (tid & 15) * 4;
            *(float4*)&As[k][mq] = *(const float4*)(Ab + (size_t)(k0 + k) * lda + m0 + mq);
        }
        if (TB == 0) {
            int k = tid >> 4, nq = (tid & 15) * 4;
            *(float4*)&Bs[k][nq] = *(const float4*)(Bb + (size_t)(k0 + k) * ldb + n0 + nq);
        } else {
            int nn = tid >> 2, kq = (tid & 3) * 4;
            float4 v = *(const float4*)(Bb + (size_t)(n0 + nn) * ldb + k0 + kq);
            Bs[kq + 0][nn] = v.x; Bs[kq + 1][nn] = v.y; Bs[kq + 2][nn] = v.z; Bs[kq + 3][nn] = v.w;
        }
        __syncthreads();
#pragma unroll
        for (int k = 0; k < 16; ++k) {
            float4 a4 = *(const float4*)&As[k][tm * 4];
            float4 b4 = *(const float4*)&Bs[k][tn * 4];
            float a[4] = {a4.x, a4.y, a4.z, a4.w};
            float b[4] = {b4.x, b4.y, b4.z, b4.w};
#pragma unroll
            for (int i = 0; i < 4; ++i)
#pragma unroll
                for (int j = 0; j < 4; ++j) acc[i][j] = fmaf(a[i], b[j], acc[i][j]);
        }
        __syncthreads();
    }

#pragma unroll
    for (int i = 0; i < 4; ++i) {
        const int m = m0 + tm * 4 + i;
        const float bi = bias ? bias[m] : 0.f;
#pragma unroll
        for (int j = 0; j < 4; ++j) {
            const int n = n0 + tn * 4 + j;
            const size_t idx = (size_t)m * ldc + n;
            const float val = acc[i][j] + bi;
            if (EPI == 0) Cb[idx] = val;
            else          Cb[idx] = scalar_p[0] * val + Cb[idx];
        }
    }
}

// ---------------- row softmax (in place) ----------------
__global__ void __launch_bounds__(256) softmax_rows_kernel(float* __restrict__ P, int cols) {
    float* r = P + (size_t)blockIdx.x * cols;
    const int tid = threadIdx.x;
    __shared__ float red[4];
    __shared__ float red2[4];

    float mx = -3.4e38f;
    for (int c = tid; c < cols; c += 256) mx = fmaxf(mx, r[c]);
    for (int o = 32; o > 0; o >>= 1) mx = fmaxf(mx, __shfl_down(mx, o, 64));
    if ((tid & 63) == 0) red[tid >> 6] = mx;
    __syncthreads();
    mx = fmaxf(fmaxf(red[0], red[1]), fmaxf(red[2], red[3]));

    float s = 0.f;
    for (int c = tid; c < cols; c += 256) {
        float e = __expf(r[c] - mx);
        r[c] = e;
        s += e;
    }
    for (int o = 32; o > 0; o >>= 1) s += __shfl_down(s, o, 64);
    if ((tid & 63) == 0) red2[tid >> 6] = s;
    __syncthreads();
    s = red2[0] + red2[1] + red2[2] + red2[3];
    const float inv = 1.f / s;
    for (int c = tid; c < cols; c += 256) r[c] *= inv;
}

// ---------------- dst += scalar*src (float4) ----------------
__global__ void __launch_bounds__(256) axpy_kernel(
                 float* __restrict__ dst, const float* __restrict__ src,
                 const float* __restrict__ sc, int n4) {
    int i = blockIdx.x * 256 + threadIdx.x;
    if (i >= n4) return;
    float4 d = ((const float4*)dst)[i];
    float4 s = ((const float4*)src)[i];
    float b = sc[0];
    d.x += b * s.x; d.y += b * s.y; d.z += b * s.z; d.w += b * s.w;
    ((float4*)dst)[i] = d;
}

extern "C" void kernel_launch(void* const* d_in, const int* in_sizes, int n_in,
                              void* d_out, int out_size, void* d_ws, size_t ws_size,
                              hipStream_t stream) {
    const float* x     = (const float*)d_in[0];
    const float* sa_w1 = (const float*)d_in[1];
    const float* sa_g1 = (const float*)d_in[2];
    const float* sa_b1 = (const float*)d_in[3];
    const float* sa_m1 = (const float*)d_in[4];
    const float* sa_v1 = (const float*)d_in[5];
    const float* q_w   = (const float*)d_in[6];
    const float* q_b   = (const float*)d_in[7];
    const float* k_w   = (const float*)d_in[8];
    const float* k_b   = (const float*)d_in[9];
    const float* v_w   = (const float*)d_in[10];
    const float* v_b   = (const float*)d_in[11];
    const float* alpha = (const float*)d_in[12];
    const float* sa_w2 = (const float*)d_in[13];
    const float* sa_g2 = (const float*)d_in[14];
    const float* sa_b2 = (const float*)d_in[15];
    const float* sa_m2 = (const float*)d_in[16];
    const float* sa_v2 = (const float*)d_in[17];
    const float* ca_w1 = (const float*)d_in[18];
    const float* ca_g1 = (const float*)d_in[19];
    const float* ca_b1 = (const float*)d_in[20];
    const float* ca_m1 = (const float*)d_in[21];
    const float* ca_v1 = (const float*)d_in[22];
    const float* beta  = (const float*)d_in[23];
    const float* ca_w2 = (const float*)d_in[24];
    const float* ca_g2 = (const float*)d_in[25];
    const float* ca_b2 = (const float*)d_in[26];
    const float* ca_m2 = (const float*)d_in[27];
    const float* ca_v2 = (const float*)d_in[28];

    float* out = (float*)d_out;      // fp32 output: [4,512,64,64] = 8388608 floats

    // workspace layout (floats) — total 47,448,064 floats = 181 MB
    float* ws  = (float*)d_ws;
    float* WP  = ws;                 // 2359296   (reused for all 4 convs, sequential)
    float* S1  = WP + 2359296;       // 8388608
    float* C1  = S1 + 8388608;       // 8388608
    float* V   = C1 + 8388608;       // 8388608   (reused as `co` in channel branch)
    float* Q   = V + 8388608;        // 1048576
    float* Kb  = Q + 1048576;        // 1048576
    float* G   = Kb + 1048576;       // 1048576
    float* ATT = G + 1048576;        // 16777216  (per-batch S x S)

    const long IMG = 512L * 4096;    // per-batch image stride
    const long QS  = 64L * 4096;
    dim3 cgrid(64, 8, 4);

    // 1. s1 = BNReLU(conv(x, sa_w1)) ; c1 = BNReLU(conv(x, ca_w1))
    pack_w_kernel<<<9216, 256, 0, stream>>>(sa_w1, WP);
    conv_bnrelu_kernel<<<cgrid, 256, 0, stream>>>(x, WP, sa_g1, sa_b1, sa_m1, sa_v1, S1, 0);
    pack_w_kernel<<<9216, 256, 0, stream>>>(ca_w1, WP);
    conv_bnrelu_kernel<<<cgrid, 256, 0, stream>>>(x, WP, ca_g1, ca_b1, ca_m1, ca_v1, C1, 0);

    // 2. q, k, v projections (batched via grid.z)
    gemm_kernel<0, 0, 0><<<dim3(64, 1, 4), 256, 0, stream>>>(
        q_w, 512, 0, S1, 4096, IMG, Q, 4096, QS, 512, q_b, nullptr);
    gemm_kernel<0, 0, 0><<<dim3(64, 1, 4), 256, 0, stream>>>(
        k_w, 512, 0, S1, 4096, IMG, Kb, 4096, QS, 512, k_b, nullptr);
    gemm_kernel<0, 0, 0><<<dim3(64, 8, 4), 256, 0, stream>>>(
        v_w, 512, 0, S1, 4096, IMG, V, 4096, IMG, 512, v_b, nullptr);

    // 3. spatial attention per batch: att = softmax(q^T k); s1 += alpha * (v att^T)
    for (int b = 0; b < 4; ++b) {
        gemm_kernel<1, 0, 0><<<dim3(64, 64, 1), 256, 0, stream>>>(
            Q + b * QS, 4096, 0, Kb + b * QS, 4096, 0, ATT, 4096, 0, 64, nullptr, nullptr);
        softmax_rows_kernel<<<4096, 256, 0, stream>>>(ATT, 4096);
        gemm_kernel<0, 1, 1><<<dim3(64, 8, 1), 256, 0, stream>>>(
            V + b * IMG, 4096, 0, ATT, 4096, 0, S1 + b * IMG, 4096, 0, 4096, nullptr, alpha);
    }

    // 4. sa_out = BNReLU(conv(s1, sa_w2)) -> fp32 directly into d_out
    pack_w_kernel<<<9216, 256, 0, stream>>>(sa_w2, WP);
    conv_bnrelu_kernel<<<cgrid, 256, 0, stream>>>(S1, WP, sa_g2, sa_b2, sa_m2, sa_v2, out, 0);

    // 5. channel attention: G = cf cf^T ; softmax rows ; co = G_sm cf (into V) ; c1 += beta*co
    gemm_kernel<0, 1, 0><<<dim3(8, 8, 4), 256, 0, stream>>>(
        C1, 4096, IMG, C1, 4096, IMG, G, 512, 262144, 4096, nullptr, nullptr);
    softmax_rows_kernel<<<2048, 256, 0, stream>>>(G, 512);
    gemm_kernel<0, 0, 0><<<dim3(64, 8, 4), 256, 0, stream>>>(
        G, 512, 262144, C1, 4096, IMG, V, 4096, IMG, 512, nullptr, nullptr);
    axpy_kernel<<<8192, 256, 0, stream>>>(C1, V, beta, 2097152);

    // 6. out += BNReLU(conv(c1, ca_w2))   (in-place fp32 accumulate)
    pack_w_kernel<<<9216, 256, 0, stream>>>(ca_w2, WP);
    conv_bnrelu_kernel<<<cgrid, 256, 0, stream>>>(C1, WP, ca_g2, ca_b2, ca_m2, ca_v2, out, 2);
}

// Round 6
// 1465.102 us; speedup vs baseline: 4.2539x; 4.2539x over previous
//
#include <hip/hip_runtime.h>
#include <hip/hip_bf16.h>

// B=4, C=512, H=W=64, S=4096, CI=64.  Heavy GEMMs in bf16 MFMA, rest fp32.
#define EPS_ 1e-5f

typedef __attribute__((ext_vector_type(4))) float f32x4;
typedef __attribute__((ext_vector_type(8))) short s16x8;
typedef unsigned short u16;

__device__ __forceinline__ float bf2f(u16 u) { return __uint_as_float(((unsigned)u) << 16); }
__device__ __forceinline__ u16 f2bf(float f) { __hip_bfloat16 h = __float2bfloat16(f); return *(u16*)&h; }

typedef __attribute__((address_space(3))) unsigned int lds_u32;
typedef const __attribute__((address_space(1))) unsigned int glb_u32;
__device__ __forceinline__ void gload16(const u16* g, u16* l) {
    __builtin_amdgcn_global_load_lds((glb_u32*)g, (lds_u32*)l, 16, 0, 0);
}

// ---------------- zero fill (uint4) ----------------
__global__ void __launch_bounds__(256) zero_kernel(uint4* __restrict__ p, int n) {
    int i = blockIdx.x * 256 + threadIdx.x;
    if (i < n) p[i] = make_uint4(0, 0, 0, 0);
}

// ------------- weight pack OIHW fp32 -> [9][512 o][512 ci] bf16 -------------
__global__ void __launch_bounds__(256) wpack_kernel(const float* __restrict__ w, u16* __restrict__ wp) {
    int gid = blockIdx.x * 256 + threadIdx.x;
    if (gid >= 9 * 512 * 512) return;
    int tap = gid >> 18, rem = gid & 262143;
    int o = rem >> 9, c = rem & 511;
    wp[gid] = f2bf(w[(o * 512 + c) * 9 + tap]);
}

// ------------- fp32 [n] -> bf16 [n] (v_w pack) -------------
__global__ void __launch_bounds__(256) cvtb_kernel(const float* __restrict__ a, u16* __restrict__ o, int n) {
    int i = blockIdx.x * 256 + threadIdx.x;
    if (i < n) o[i] = f2bf(a[i]);
}

// ------------- NCHW fp32 -> channel-last bf16 (padded [66][66][512] or compact [4096][512]) -------------
__global__ void __launch_bounds__(256) tcl_kernel(const float* __restrict__ X, u16* __restrict__ out, int padded) {
    __shared__ float T[64][65];
    const int b = blockIdx.z, y = blockIdx.y, c0 = blockIdx.x * 64;
    const int tid = threadIdx.x;
    const int rr = tid >> 2, q = (tid & 3) * 16;
    const float* src = X + (((size_t)(b * 512 + c0 + rr) * 64 + y) * 64) + q;
#pragma unroll
    for (int i = 0; i < 4; ++i) {
        float4 f = *(const float4*)(src + i * 4);
        T[rr][q + i * 4 + 0] = f.x; T[rr][q + i * 4 + 1] = f.y;
        T[rr][q + i * 4 + 2] = f.z; T[rr][q + i * 4 + 3] = f.w;
    }
    __syncthreads();
    u16 v[16];
#pragma unroll
    for (int i = 0; i < 16; ++i) v[i] = f2bf(T[q + i][rr]);
    u16* dst = padded ? out + ((size_t)((b * 66 + y + 1) * 66 + rr + 1)) * 512 + c0 + q
                      : out + ((size_t)(b * 4096 + y * 64 + rr)) * 512 + c0 + q;
    *(s16x8*)dst       = *(s16x8*)&v[0];
    *(s16x8*)(dst + 8) = *(s16x8*)&v[8];
}

// ---------------- conv3x3 bf16 MFMA (implicit GEMM over padded channel-last) ----------------
// Tcl: [4][66][66][512] bf16.  Wb: [9][512 o][512 ci] bf16.  Y: [4][512][4096] fp32.
// MODE 0: Y = bnrelu(acc);  MODE 2: Y += bnrelu(acc)
template <int MODE>
__global__ void __launch_bounds__(256) conv_mfma_kernel(
        const u16* __restrict__ Tcl, const u16* __restrict__ Wb,
        const float* __restrict__ gg, const float* __restrict__ bb,
        const float* __restrict__ mn, const float* __restrict__ vr,
        float* __restrict__ Y) {
    __shared__ __align__(16) u16 Ash[4096];   // [128 m][32 k]
    __shared__ __align__(16) u16 Bsh[4096];   // [128 n][32 k]
    const int tid = threadIdx.x, lane = tid & 63, wid = tid >> 6;
    const int wm = wid >> 1, wn = wid & 1;
    const int b = blockIdx.z, m0 = blockIdx.y * 128, s0 = blockIdx.x * 128;
    const int y0 = s0 >> 6;                    // tile covers image rows y0, y0+1

    const int off0 = wid * 1024 + lane * 16;   // LDS byte offset, call 0
    const int row0 = off0 >> 6, kb0 = (off0 & 63) >> 1;
    const int x_im = row0 & 63;
    // A source (weights), per call; advance by k0 and tap
    const size_t aoff0 = (size_t)(m0 + row0) * 512 + kb0;
    const size_t aoff1 = aoff0 + (size_t)64 * 512;
    // B source (activations): call0 -> image row y0, call1 -> y0+1
    const size_t bbase0 = ((size_t)(b * 66 + y0 + 1) * 66 + x_im + 1) * 512 + kb0;
    const size_t bbase1 = ((size_t)(b * 66 + y0 + 2) * 66 + x_im + 1) * 512 + kb0;
    u16* ldsA0 = Ash + wid * 512; u16* ldsA1 = ldsA0 + 2048;
    u16* ldsB0 = Bsh + wid * 512; u16* ldsB1 = ldsB0 + 2048;

    f32x4 acc[4][4];
#pragma unroll
    for (int i = 0; i < 4; ++i)
#pragma unroll
        for (int j = 0; j < 4; ++j) acc[i][j] = (f32x4){0.f, 0.f, 0.f, 0.f};

    const int ra = wm * 64 + (lane & 15);      // A row base (+i*16)
    const int rb = wn * 64 + (lane & 15);      // B row base (+j*16)
    const int kq = (lane >> 4) * 8;

    for (int tap = 0; tap < 9; ++tap) {
        const u16* At = Wb + (size_t)tap * 262144;
        const long bshift = (long)((tap / 3 - 1) * 66 + (tap % 3 - 1)) * 512;
        const u16* Bt0 = Tcl + bbase0 + bshift;
        const u16* Bt1 = Tcl + bbase1 + bshift;
        for (int k0 = 0; k0 < 512; k0 += 32) {
            gload16(At + aoff0 + k0, ldsA0);
            gload16(At + aoff1 + k0, ldsA1);
            gload16(Bt0 + k0, ldsB0);
            gload16(Bt1 + k0, ldsB1);
            __syncthreads();
            s16x8 a[4], bf[4];
#pragma unroll
            for (int i = 0; i < 4; ++i) a[i]  = *(const s16x8*)&Ash[(ra + i * 16) * 32 + kq];
#pragma unroll
            for (int j = 0; j < 4; ++j) bf[j] = *(const s16x8*)&Bsh[(rb + j * 16) * 32 + kq];
#pragma unroll
            for (int i = 0; i < 4; ++i)
#pragma unroll
                for (int j = 0; j < 4; ++j)
                    acc[i][j] = __builtin_amdgcn_mfma_f32_16x16x32_bf16(a[i], bf[j], acc[i][j], 0, 0, 0);
            __syncthreads();
        }
    }

#pragma unroll
    for (int i = 0; i < 4; ++i) {
#pragma unroll
        for (int r = 0; r < 4; ++r) {
            const int c = m0 + wm * 64 + i * 16 + (lane >> 4) * 4 + r;
            const float sc = gg[c] * rsqrtf(vr[c] + EPS_);
            const float bn = bb[c] - mn[c] * sc;
            const size_t rowi = ((size_t)(b * 512 + c)) * 4096;
#pragma unroll
            for (int j = 0; j < 4; ++j) {
                const int s = s0 + wn * 64 + j * 16 + (lane & 15);
                const float v = fmaxf(acc[i][j][r] * sc + bn, 0.f);
                if (MODE == 0) Y[rowi + s] = v;
                else           Y[rowi + s] += v;
            }
        }
    }
}

// ---------------- generic bf16 MFMA NT GEMM: D[m][n] = sum_k A[m][k] B[n][k] ----------------
// EPI 0: (bf16*)C = acc + bias[m];  EPI 1: (float*)C += scalar * acc
template <int EPI>
__global__ void __launch_bounds__(256) mfma_nt_kernel(
        const u16* __restrict__ A, int lda, long sA,
        const u16* __restrict__ Bm, int ldb, long sB,
        void* __restrict__ C, int ldc, long sC,
        int K, const float* __restrict__ bias, const float* __restrict__ scalar_p) {
    __shared__ __align__(16) u16 Ash[4096];
    __shared__ __align__(16) u16 Bsh[4096];
    const int tid = threadIdx.x, lane = tid & 63, wid = tid >> 6;
    const int wm = wid >> 1, wn = wid & 1;
    const int m0 = blockIdx.y * 128, n0 = blockIdx.x * 128;
    const u16* Ab = A + (size_t)blockIdx.z * sA;
    const u16* Bb = Bm + (size_t)blockIdx.z * sB;

    const int off0 = wid * 1024 + lane * 16;
    const int row0 = off0 >> 6, kb0 = (off0 & 63) >> 1;
    const size_t aoff0 = (size_t)(m0 + row0) * lda + kb0;
    const size_t aoff1 = aoff0 + (size_t)64 * lda;
    const size_t boff0 = (size_t)(n0 + row0) * ldb + kb0;
    const size_t boff1 = boff0 + (size_t)64 * ldb;
    u16* ldsA0 = Ash + wid * 512; u16* ldsA1 = ldsA0 + 2048;
    u16* ldsB0 = Bsh + wid * 512; u16* ldsB1 = ldsB0 + 2048;

    f32x4 acc[4][4];
#pragma unroll
    for (int i = 0; i < 4; ++i)
#pragma unroll
        for (int j = 0; j < 4; ++j) acc[i][j] = (f32x4){0.f, 0.f, 0.f, 0.f};

    const int ra = wm * 64 + (lane & 15);
    const int rb = wn * 64 + (lane & 15);
    const int kq = (lane >> 4) * 8;

    for (int k0 = 0; k0 < K; k0 += 32) {
        gload16(Ab + aoff0 + k0, ldsA0);
        gload16(Ab + aoff1 + k0, ldsA1);
        gload16(Bb + boff0 + k0, ldsB0);
        gload16(Bb + boff1 + k0, ldsB1);
        __syncthreads();
        s16x8 a[4], bf[4];
#pragma unroll
        for (int i = 0; i < 4; ++i) a[i]  = *(const s16x8*)&Ash[(ra + i * 16) * 32 + kq];
#pragma unroll
        for (int j = 0; j < 4; ++j) bf[j] = *(const s16x8*)&Bsh[(rb + j * 16) * 32 + kq];
#pragma unroll
        for (int i = 0; i < 4; ++i)
#pragma unroll
            for (int j = 0; j < 4; ++j)
                acc[i][j] = __builtin_amdgcn_mfma_f32_16x16x32_bf16(a[i], bf[j], acc[i][j], 0, 0, 0);
        __syncthreads();
    }

#pragma unroll
    for (int i = 0; i < 4; ++i) {
#pragma unroll
        for (int r = 0; r < 4; ++r) {
            const int m = m0 + wm * 64 + i * 16 + (lane >> 4) * 4 + r;
            const float bi = (EPI == 0 && bias) ? bias[m] : 0.f;
#pragma unroll
            for (int j = 0; j < 4; ++j) {
                const int n = n0 + wn * 64 + j * 16 + (lane & 15);
                const size_t idx = (size_t)blockIdx.z * sC + (size_t)m * ldc + n;
                if (EPI == 0) ((u16*)C)[idx] = f2bf(acc[i][j][r] + bi);
                else          ((float*)C)[idx] += scalar_p[0] * acc[i][j][r];
            }
        }
    }
}

// ---------------- fp32 64x64 tiled GEMM (small ops: q/k proj, QK^T, G) ----------------
// EPI 0: C = acc + bias[m] (fp32).  EPI 2: (bf16*)C = acc + bias[m].
template <int TA, int TB, int EPI>
__global__ void __launch_bounds__(256) gemm_kernel(
                 const float* __restrict__ A, int lda, long sA,
                 const float* __restrict__ B, int ldb, long sB,
                 float* __restrict__ C, int ldc, long sC,
                 int K, const float* __restrict__ bias) {
    __shared__ float As[16][68];
    __shared__ float Bs[16][68];
    const float* Ab = A + (size_t)blockIdx.z * sA;
    const float* Bb = B + (size_t)blockIdx.z * sB;
    const int m0 = blockIdx.y * 64, n0 = blockIdx.x * 64;
    const int tid = threadIdx.x;
    const int tm = tid >> 4, tn = tid & 15;

    float acc[4][4];
#pragma unroll
    for (int i = 0; i < 4; ++i)
#pragma unroll
        for (int j = 0; j < 4; ++j) acc[i][j] = 0.f;

    for (int k0 = 0; k0 < K; k0 += 16) {
        if (TA == 0) {
            int m = tid >> 2, kq = (tid & 3) * 4;
            float4 v = *(const float4*)(Ab + (size_t)(m0 + m) * lda + k0 + kq);
            As[kq + 0][m] = v.x; As[kq + 1][m] = v.y; As[kq + 2][m] = v.z; As[kq + 3][m] = v.w;
        } else {
            int k = tid >> 4, mq = (tid & 15) * 4;
            *(float4*)&As[k][mq] = *(const float4*)(Ab + (size_t)(k0 + k) * lda + m0 + mq);
        }
        if (TB == 0) {
            int k = tid >> 4, nq = (tid & 15) * 4;
            *(float4*)&Bs[k][nq] = *(const float4*)(Bb + (size_t)(k0 + k) * ldb + n0 + nq);
        } else {
            int nn = tid >> 2, kq = (tid & 3) * 4;
            float4 v = *(const float4*)(Bb + (size_t)(n0 + nn) * ldb + k0 + kq);
            Bs[kq + 0][nn] = v.x; Bs[kq + 1][nn] = v.y; Bs[kq + 2][nn] = v.z; Bs[kq + 3][nn] = v.w;
        }
        __syncthreads();
#pragma unroll
        for (int k = 0; k < 16; ++k) {
            float4 a4 = *(const float4*)&As[k][tm * 4];
            float4 b4 = *(const float4*)&Bs[k][tn * 4];
            float a[4] = {a4.x, a4.y, a4.z, a4.w};
            float b[4] = {b4.x, b4.y, b4.z, b4.w};
#pragma unroll
            for (int i = 0; i < 4; ++i)
#pragma unroll
                for (int j = 0; j < 4; ++j) acc[i][j] = fmaf(a[i], b[j], acc[i][j]);
        }
        __syncthreads();
    }

#pragma unroll
    for (int i = 0; i < 4; ++i) {
        const int m = m0 + tm * 4 + i;
        const float bi = bias ? bias[m] : 0.f;
#pragma unroll
        for (int j = 0; j < 4; ++j) {
            const int n = n0 + tn * 4 + j;
            const size_t idx = (size_t)blockIdx.z * sC + (size_t)m * ldc + n;
            const float val = acc[i][j] + bi;
            if (EPI == 0) C[idx] = val;
            else          ((u16*)C)[idx] = f2bf(val);
        }
    }
}

// ---------------- softmax over bf16 rows of 4096, in place ----------------
__global__ void __launch_bounds__(256) softmax_att_kernel(u16* __restrict__ P) {
    u16* r = P + (size_t)blockIdx.x * 4096;
    const int tid = threadIdx.x;
    __shared__ float red[4], red2[4];
    float v[16];
    {
        s16x8 h0 = *(const s16x8*)(r + tid * 16);
        s16x8 h1 = *(const s16x8*)(r + tid * 16 + 8);
#pragma unroll
        for (int i = 0; i < 8; ++i) { v[i] = bf2f((u16)h0[i]); v[8 + i] = bf2f((u16)h1[i]); }
    }
    float mx = v[0];
#pragma unroll
    for (int i = 1; i < 16; ++i) mx = fmaxf(mx, v[i]);
    for (int o = 32; o > 0; o >>= 1) mx = fmaxf(mx, __shfl_down(mx, o, 64));
    if ((tid & 63) == 0) red[tid >> 6] = mx;
    __syncthreads();
    mx = fmaxf(fmaxf(red[0], red[1]), fmaxf(red[2], red[3]));
    float s = 0.f;
#pragma unroll
    for (int i = 0; i < 16; ++i) { v[i] = __expf(v[i] - mx); s += v[i]; }
    for (int o = 32; o > 0; o >>= 1) s += __shfl_down(s, o, 64);
    if ((tid & 63) == 0) red2[tid >> 6] = s;
    __syncthreads();
    s = red2[0] + red2[1] + red2[2] + red2[3];
    const float inv = 1.f / s;
    u16 w[16];
#pragma unroll
    for (int i = 0; i < 16; ++i) w[i] = f2bf(v[i] * inv);
    *(s16x8*)(r + tid * 16)     = *(s16x8*)&w[0];
    *(s16x8*)(r + tid * 16 + 8) = *(s16x8*)&w[8];
}

// ---------------- softmax fp32 rows of 512 -> bf16 out ----------------
__global__ void __launch_bounds__(256) softmax_g_kernel(const float* __restrict__ G, u16* __restrict__ Gs) {
    const float* r = G + (size_t)blockIdx.x * 512;
    u16* o = Gs + (size_t)blockIdx.x * 512;
    const int tid = threadIdx.x;
    __shared__ float red[4], red2[4];
    float2 v = *(const float2*)(r + tid * 2);
    float mx = fmaxf(v.x, v.y);
    for (int off = 32; off > 0; off >>= 1) mx = fmaxf(mx, __shfl_down(mx, off, 64));
    if ((tid & 63) == 0) red[tid >> 6] = mx;
    __syncthreads();
    mx = fmaxf(fmaxf(red[0], red[1]), fmaxf(red[2], red[3]));
    float e0 = __expf(v.x - mx), e1 = __expf(v.y - mx);
    float s = e0 + e1;
    for (int off = 32; off > 0; off >>= 1) s += __shfl_down(s, off, 64);
    if ((tid & 63) == 0) red2[tid >> 6] = s;
    __syncthreads();
    s = red2[0] + red2[1] + red2[2] + red2[3];
    const float inv = 1.f / s;
    o[tid * 2] = f2bf(e0 * inv);
    o[tid * 2 + 1] = f2bf(e1 * inv);
}

extern "C" void kernel_launch(void* const* d_in, const int* in_sizes, int n_in,
                              void* d_out, int out_size, void* d_ws, size_t ws_size,
                              hipStream_t stream) {
    const float* x     = (const float*)d_in[0];
    const float* sa_w1 = (const float*)d_in[1];
    const float* sa_g1 = (const float*)d_in[2];
    const float* sa_b1 = (const float*)d_in[3];
    const float* sa_m1 = (const float*)d_in[4];
    const float* sa_v1 = (const float*)d_in[5];
    const float* q_w   = (const float*)d_in[6];
    const float* q_b   = (const float*)d_in[7];
    const float* k_w   = (const float*)d_in[8];
    const float* k_b   = (const float*)d_in[9];
    const float* v_w   = (const float*)d_in[10];
    const float* v_b   = (const float*)d_in[11];
    const float* alpha = (const float*)d_in[12];
    const float* sa_w2 = (const float*)d_in[13];
    const float* sa_g2 = (const float*)d_in[14];
    const float* sa_b2 = (const float*)d_in[15];
    const float* sa_m2 = (const float*)d_in[16];
    const float* sa_v2 = (const float*)d_in[17];
    const float* ca_w1 = (const float*)d_in[18];
    const float* ca_g1 = (const float*)d_in[19];
    const float* ca_b1 = (const float*)d_in[20];
    const float* ca_m1 = (const float*)d_in[21];
    const float* ca_v1 = (const float*)d_in[22];
    const float* beta  = (const float*)d_in[23];
    const float* ca_w2 = (const float*)d_in[24];
    const float* ca_g2 = (const float*)d_in[25];
    const float* ca_b2 = (const float*)d_in[26];
    const float* ca_m2 = (const float*)d_in[27];
    const float* ca_v2 = (const float*)d_in[28];

    float* out = (float*)d_out;

    // ---- workspace layout: floats first, then bf16. Total ~164 MB ----
    char* wsb = (char*)d_ws;
    float* S1f = (float*)wsb;                 wsb += 8388608ull * 4;   // [4][512][4096]
    float* C1f = (float*)wsb;                 wsb += 8388608ull * 4;
    float* Q   = (float*)wsb;                 wsb += 1048576ull * 4;   // [4][64][4096]
    float* Kb  = (float*)wsb;                 wsb += 1048576ull * 4;
    float* G   = (float*)wsb;                 wsb += 1048576ull * 4;   // [4][512][512]
    u16* Tcl   = (u16*)wsb;                   wsb += 8921088ull * 2;   // [4][66][66][512]
    u16* CLB   = (u16*)wsb;                   wsb += 8388608ull * 2;   // [4][4096][512]
    u16* Wb    = (u16*)wsb;                   wsb += 2359296ull * 2;   // [9][512][512]
    u16* VWb   = (u16*)wsb;                   wsb += 262144ull * 2;    // [512][512]
    u16* Vb    = (u16*)wsb;                   wsb += 8388608ull * 2;   // [4][512][4096]
    u16* ATT   = (u16*)wsb;                   wsb += 16777216ull * 2;  // [4096][4096] per-batch reuse
    u16* Gsb   = (u16*)wsb;                   wsb += 1048576ull * 2;   // [4][512][512]

    const long IMG = 512L * 4096;
    const long QS  = 64L * 4096;
    dim3 cgrid(32, 4, 4);     // conv: s-tiles(128) x m-tiles(128) x batch
    dim3 tgrid(8, 64, 4);     // transpose

    // 0. zero padded channel-last buffer (borders stay 0 forever)
    zero_kernel<<<4357, 256, 0, stream>>>((uint4*)Tcl, 1115136);

    // 1. conv1 both branches from x
    tcl_kernel<<<tgrid, 256, 0, stream>>>(x, Tcl, 1);
    wpack_kernel<<<9216, 256, 0, stream>>>(sa_w1, Wb);
    conv_mfma_kernel<0><<<cgrid, 256, 0, stream>>>(Tcl, Wb, sa_g1, sa_b1, sa_m1, sa_v1, S1f);
    wpack_kernel<<<9216, 256, 0, stream>>>(ca_w1, Wb);
    conv_mfma_kernel<0><<<cgrid, 256, 0, stream>>>(Tcl, Wb, ca_g1, ca_b1, ca_m1, ca_v1, C1f);

    // 2. q, k projections (fp32, read S1f)
    gemm_kernel<0, 0, 0><<<dim3(64, 1, 4), 256, 0, stream>>>(
        q_w, 512, 0, S1f, 4096, IMG, Q, 4096, QS, 512, q_b);
    gemm_kernel<0, 0, 0><<<dim3(64, 1, 4), 256, 0, stream>>>(
        k_w, 512, 0, S1f, 4096, IMG, Kb, 4096, QS, 512, k_b);

    // 3. v projection (bf16): A=VWb [512][512], B=S1 compact channel-last -> Vb bf16
    cvtb_kernel<<<1024, 256, 0, stream>>>(v_w, VWb, 262144);
    tcl_kernel<<<tgrid, 256, 0, stream>>>(S1f, CLB, 0);
    mfma_nt_kernel<0><<<dim3(32, 4, 4), 256, 0, stream>>>(
        VWb, 512, 0, CLB, 512, 2097152, Vb, 4096, 2097152, 512, v_b, nullptr);

    // 4. spatial attention per batch
    for (int b = 0; b < 4; ++b) {
        gemm_kernel<1, 0, 2><<<dim3(64, 64, 1), 256, 0, stream>>>(
            Q + b * QS, 4096, 0, Kb + b * QS, 4096, 0, (float*)ATT, 4096, 0, 64, nullptr);
        softmax_att_kernel<<<4096, 256, 0, stream>>>(ATT);
        mfma_nt_kernel<1><<<dim3(32, 4, 1), 256, 0, stream>>>(
            Vb + b * 2097152, 4096, 0, ATT, 4096, 0, S1f + b * IMG, 4096, 0, 4096, nullptr, alpha);
    }

    // 5. sa_out = BNReLU(conv(s1, sa_w2)) -> d_out (fp32 write)
    tcl_kernel<<<tgrid, 256, 0, stream>>>(S1f, Tcl, 1);
    wpack_kernel<<<9216, 256, 0, stream>>>(sa_w2, Wb);
    conv_mfma_kernel<0><<<cgrid, 256, 0, stream>>>(Tcl, Wb, sa_g2, sa_b2, sa_m2, sa_v2, out);

    // 6. channel attention: G = cf cf^T (fp32); row softmax -> bf16; c1 += beta * (G_sm cf)
    gemm_kernel<0, 1, 0><<<dim3(8, 8, 4), 256, 0, stream>>>(
        C1f, 4096, IMG, C1f, 4096, IMG, G, 512, 262144, 4096, nullptr);
    softmax_g_kernel<<<2048, 256, 0, stream>>>(G, Gsb);
    tcl_kernel<<<tgrid, 256, 0, stream>>>(C1f, CLB, 0);
    mfma_nt_kernel<1><<<dim3(32, 4, 4), 256, 0, stream>>>(
        Gsb, 512, 262144, CLB, 512, 2097152, C1f, 4096, IMG, 512, nullptr, beta);

    // 7. out += BNReLU(conv(c1, ca_w2))
    tcl_kernel<<<tgrid, 256, 0, stream>>>(C1f, Tcl, 1);
    wpack_kernel<<<9216, 256, 0, stream>>>(ca_w2, Wb);
    conv_mfma_kernel<2><<<cgrid, 256, 0, stream>>>(Tcl, Wb, ca_g2, ca_b2, ca_m2, ca_v2, out);
}

// Round 9
// 1289.783 us; speedup vs baseline: 4.8321x; 1.1359x over previous
//
#include <hip/hip_runtime.h>
#include <hip/hip_bf16.h>

// B=4, C=512, H=W=64, S=4096, CI=64.  Heavy GEMMs in bf16 MFMA, rest fp32.
#define EPS_ 1e-5f

typedef __attribute__((ext_vector_type(4))) float f32x4;
typedef __attribute__((ext_vector_type(8))) short s16x8;
typedef unsigned short u16;

__device__ __forceinline__ float bf2f(u16 u) { return __uint_as_float(((unsigned)u) << 16); }
__device__ __forceinline__ u16 f2bf(float f) { __hip_bfloat16 h = __float2bfloat16(f); return *(u16*)&h; }

typedef __attribute__((address_space(3))) unsigned int lds_u32;
typedef const __attribute__((address_space(1))) unsigned int glb_u32;
__device__ __forceinline__ void gload16(const u16* g, u16* l) {
    __builtin_amdgcn_global_load_lds((glb_u32*)g, (lds_u32*)l, 16, 0, 0);
}

// ---------------- zero fill (uint4) ----------------
__global__ void __launch_bounds__(256) zero_kernel(uint4* __restrict__ p, int n) {
    int i = blockIdx.x * 256 + threadIdx.x;
    if (i < n) p[i] = make_uint4(0, 0, 0, 0);
}

// ------------- weight pack OIHW fp32 -> [9][512 o][512 ci] bf16 -------------
__global__ void __launch_bounds__(256) wpack_kernel(const float* __restrict__ w, u16* __restrict__ wp) {
    int gid = blockIdx.x * 256 + threadIdx.x;
    if (gid >= 9 * 512 * 512) return;
    int tap = gid >> 18, rem = gid & 262143;
    int o = rem >> 9, c = rem & 511;
    wp[gid] = f2bf(w[(o * 512 + c) * 9 + tap]);
}

// ------------- fp32 [n] -> bf16 [n] -------------
__global__ void __launch_bounds__(256) cvtb_kernel(const float* __restrict__ a, u16* __restrict__ o, int n) {
    int i = blockIdx.x * 256 + threadIdx.x;
    if (i < n) o[i] = f2bf(a[i]);
}

// ------------- NCHW fp32 -> channel-last bf16 (padded [66][66][512] or compact [4096][512]) -------------
__global__ void __launch_bounds__(256) tcl_kernel(const float* __restrict__ X, u16* __restrict__ out, int padded) {
    __shared__ float T[64][65];
    const int b = blockIdx.z, y = blockIdx.y, c0 = blockIdx.x * 64;
    const int tid = threadIdx.x;
    const int rr = tid >> 2, q = (tid & 3) * 16;
    const float* src = X + (((size_t)(b * 512 + c0 + rr) * 64 + y) * 64) + q;
#pragma unroll
    for (int i = 0; i < 4; ++i) {
        float4 f = *(const float4*)(src + i * 4);
        T[rr][q + i * 4 + 0] = f.x; T[rr][q + i * 4 + 1] = f.y;
        T[rr][q + i * 4 + 2] = f.z; T[rr][q + i * 4 + 3] = f.w;
    }
    __syncthreads();
    u16 v[16];
#pragma unroll
    for (int i = 0; i < 16; ++i) v[i] = f2bf(T[q + i][rr]);
    u16* dst = padded ? out + ((size_t)((b * 66 + y + 1) * 66 + rr + 1)) * 512 + c0 + q
                      : out + ((size_t)(b * 4096 + y * 64 + rr)) * 512 + c0 + q;
    *(s16x8*)dst       = *(s16x8*)&v[0];
    *(s16x8*)(dst + 8) = *(s16x8*)&v[8];
}

// ---------------- conv3x3 bf16 MFMA (implicit GEMM over padded channel-last) ----------------
template <int MODE>   // 0: Y = bnrelu; 2: Y += bnrelu
__global__ void __launch_bounds__(256) conv_mfma_kernel(
        const u16* __restrict__ Tcl, const u16* __restrict__ Wb,
        const float* __restrict__ gg, const float* __restrict__ bb,
        const float* __restrict__ mn, const float* __restrict__ vr,
        float* __restrict__ Y) {
    __shared__ __align__(16) u16 Ash[4096];   // [128 m][32 k]
    __shared__ __align__(16) u16 Bsh[4096];   // [128 n][32 k]
    const int tid = threadIdx.x, lane = tid & 63, wid = tid >> 6;
    const int wm = wid >> 1, wn = wid & 1;
    const int b = blockIdx.z, m0 = blockIdx.y * 128, s0 = blockIdx.x * 128;
    const int y0 = s0 >> 6;

    const int off0 = wid * 1024 + lane * 16;
    const int row0 = off0 >> 6, kb0 = (off0 & 63) >> 1;
    const int x_im = row0 & 63;
    const size_t aoff0 = (size_t)(m0 + row0) * 512 + kb0;
    const size_t aoff1 = aoff0 + (size_t)64 * 512;
    const size_t bbase0 = ((size_t)(b * 66 + y0 + 1) * 66 + x_im + 1) * 512 + kb0;
    const size_t bbase1 = ((size_t)(b * 66 + y0 + 2) * 66 + x_im + 1) * 512 + kb0;
    u16* ldsA0 = Ash + wid * 512; u16* ldsA1 = ldsA0 + 2048;
    u16* ldsB0 = Bsh + wid * 512; u16* ldsB1 = ldsB0 + 2048;

    f32x4 acc[4][4];
#pragma unroll
    for (int i = 0; i < 4; ++i)
#pragma unroll
        for (int j = 0; j < 4; ++j) acc[i][j] = (f32x4){0.f, 0.f, 0.f, 0.f};

    const int ra = wm * 64 + (lane & 15);
    const int rb = wn * 64 + (lane & 15);
    const int kq = (lane >> 4) * 8;

    for (int tap = 0; tap < 9; ++tap) {
        const u16* At = Wb + (size_t)tap * 262144;
        const long bshift = (long)((tap / 3 - 1) * 66 + (tap % 3 - 1)) * 512;
        const u16* Bt0 = Tcl + bbase0 + bshift;
        const u16* Bt1 = Tcl + bbase1 + bshift;
        for (int k0 = 0; k0 < 512; k0 += 32) {
            gload16(At + aoff0 + k0, ldsA0);
            gload16(At + aoff1 + k0, ldsA1);
            gload16(Bt0 + k0, ldsB0);
            gload16(Bt1 + k0, ldsB1);
            __syncthreads();
            s16x8 a[4], bf[4];
#pragma unroll
            for (int i = 0; i < 4; ++i) a[i]  = *(const s16x8*)&Ash[(ra + i * 16) * 32 + kq];
#pragma unroll
            for (int j = 0; j < 4; ++j) bf[j] = *(const s16x8*)&Bsh[(rb + j * 16) * 32 + kq];
#pragma unroll
            for (int i = 0; i < 4; ++i)
#pragma unroll
                for (int j = 0; j < 4; ++j)
                    acc[i][j] = __builtin_amdgcn_mfma_f32_16x16x32_bf16(a[i], bf[j], acc[i][j], 0, 0, 0);
            __syncthreads();
        }
    }

#pragma unroll
    for (int i = 0; i < 4; ++i) {
#pragma unroll
        for (int r = 0; r < 4; ++r) {
            const int c = m0 + wm * 64 + i * 16 + (lane >> 4) * 4 + r;
            const float sc = gg[c] * rsqrtf(vr[c] + EPS_);
            const float bn = bb[c] - mn[c] * sc;
            const size_t rowi = ((size_t)(b * 512 + c)) * 4096;
#pragma unroll
            for (int j = 0; j < 4; ++j) {
                const int s = s0 + wn * 64 + j * 16 + (lane & 15);
                const float v = fmaxf(acc[i][j][r] * sc + bn, 0.f);
                if (MODE == 0) Y[rowi + s] = v;
                else           Y[rowi + s] += v;
            }
        }
    }
}

// ---------------- generic bf16 MFMA NT GEMM: D[m][n] = sum_k A[m][k] B[n][k] ----------------
// EPI 0: (bf16*)C = acc + bias[m];  EPI 1: (float*)C += scalar*acc;  EPI 2: (float*)C = acc
template <int EPI>
__global__ void __launch_bounds__(256) mfma_nt_kernel(
        const u16* __restrict__ A, int lda, long sA,
        const u16* __restrict__ Bm, int ldb, long sB,
        void* __restrict__ C, int ldc, long sC,
        int K, const float* __restrict__ bias, const float* __restrict__ scalar_p) {
    __shared__ __align__(16) u16 Ash[4096];
    __shared__ __align__(16) u16 Bsh[4096];
    const int tid = threadIdx.x, lane = tid & 63, wid = tid >> 6;
    const int wm = wid >> 1, wn = wid & 1;
    const int m0 = blockIdx.y * 128, n0 = blockIdx.x * 128;
    const u16* Ab = A + (size_t)blockIdx.z * sA;
    const u16* Bb = Bm + (size_t)blockIdx.z * sB;

    const int off0 = wid * 1024 + lane * 16;
    const int row0 = off0 >> 6, kb0 = (off0 & 63) >> 1;
    const size_t aoff0 = (size_t)(m0 + row0) * lda + kb0;
    const size_t aoff1 = aoff0 + (size_t)64 * lda;
    const size_t boff0 = (size_t)(n0 + row0) * ldb + kb0;
    const size_t boff1 = boff0 + (size_t)64 * ldb;
    u16* ldsA0 = Ash + wid * 512; u16* ldsA1 = ldsA0 + 2048;
    u16* ldsB0 = Bsh + wid * 512; u16* ldsB1 = ldsB0 + 2048;

    f32x4 acc[4][4];
#pragma unroll
    for (int i = 0; i < 4; ++i)
#pragma unroll
        for (int j = 0; j < 4; ++j) acc[i][j] = (f32x4){0.f, 0.f, 0.f, 0.f};

    const int ra = wm * 64 + (lane & 15);
    const int rb = wn * 64 + (lane & 15);
    const int kq = (lane >> 4) * 8;

    for (int k0 = 0; k0 < K; k0 += 32) {
        gload16(Ab + aoff0 + k0, ldsA0);
        gload16(Ab + aoff1 + k0, ldsA1);
        gload16(Bb + boff0 + k0, ldsB0);
        gload16(Bb + boff1 + k0, ldsB1);
        __syncthreads();
        s16x8 a[4], bf[4];
#pragma unroll
        for (int i = 0; i < 4; ++i) a[i]  = *(const s16x8*)&Ash[(ra + i * 16) * 32 + kq];
#pragma unroll
        for (int j = 0; j < 4; ++j) bf[j] = *(const s16x8*)&Bsh[(rb + j * 16) * 32 + kq];
#pragma unroll
        for (int i = 0; i < 4; ++i)
#pragma unroll
            for (int j = 0; j < 4; ++j)
                acc[i][j] = __builtin_amdgcn_mfma_f32_16x16x32_bf16(a[i], bf[j], acc[i][j], 0, 0, 0);
        __syncthreads();
    }

#pragma unroll
    for (int i = 0; i < 4; ++i) {
#pragma unroll
        for (int r = 0; r < 4; ++r) {
            const int m = m0 + wm * 64 + i * 16 + (lane >> 4) * 4 + r;
            const float bi = (EPI == 0 && bias) ? bias[m] : 0.f;
#pragma unroll
            for (int j = 0; j < 4; ++j) {
                const int n = n0 + wn * 64 + j * 16 + (lane & 15);
                const size_t idx = (size_t)blockIdx.z * sC + (size_t)m * ldc + n;
                if (EPI == 0)      ((u16*)C)[idx] = f2bf(acc[i][j][r] + bi);
                else if (EPI == 1) ((float*)C)[idx] += scalar_p[0] * acc[i][j][r];
                else               ((float*)C)[idx] = acc[i][j][r];
            }
        }
    }
}

// ---------------- fp32 64x64 tiled GEMM ----------------
// EPI 0: fp32 C = acc + bias[m].  EPI 3: (bf16*)C = acc + bias[n].
template <int TA, int TB, int EPI>
__global__ void __launch_bounds__(256) gemm_kernel(
                 const float* __restrict__ A, int lda, long sA,
                 const float* __restrict__ B, int ldb, long sB,
                 float* __restrict__ C, int ldc, long sC,
                 int K, const float* __restrict__ bias) {
    __shared__ float As[16][68];
    __shared__ float Bs[16][68];
    const float* Ab = A + (size_t)blockIdx.z * sA;
    const float* Bb = B + (size_t)blockIdx.z * sB;
    const int m0 = blockIdx.y * 64, n0 = blockIdx.x * 64;
    const int tid = threadIdx.x;
    const int tm = tid >> 4, tn = tid & 15;

    float acc[4][4];
#pragma unroll
    for (int i = 0; i < 4; ++i)
#pragma unroll
        for (int j = 0; j < 4; ++j) acc[i][j] = 0.f;

    for (int k0 = 0; k0 < K; k0 += 16) {
        if (TA == 0) {
            int m = tid >> 2, kq = (tid & 3) * 4;
            float4 v = *(const float4*)(Ab + (size_t)(m0 + m) * lda + k0 + kq);
            As[kq + 0][m] = v.x; As[kq + 1][m] = v.y; As[kq + 2][m] = v.z; As[kq + 3][m] = v.w;
        } else {
            int k = tid >> 4, mq = (tid & 15) * 4;
            *(float4*)&As[k][mq] = *(const float4*)(Ab + (size_t)(k0 + k) * lda + m0 + mq);
        }
        if (TB == 0) {
            int k = tid >> 4, nq = (tid & 15) * 4;
            *(float4*)&Bs[k][nq] = *(const float4*)(Bb + (size_t)(k0 + k) * ldb + n0 + nq);
        } else {
            int nn = tid >> 2, kq = (tid & 3) * 4;
            float4 v = *(const float4*)(Bb + (size_t)(n0 + nn) * ldb + k0 + kq);
            Bs[kq + 0][nn] = v.x; Bs[kq + 1][nn] = v.y; Bs[kq + 2][nn] = v.z; Bs[kq + 3][nn] = v.w;
        }
        __syncthreads();
#pragma unroll
        for (int k = 0; k < 16; ++k) {
            float4 a4 = *(const float4*)&As[k][tm * 4];
            float4 b4 = *(const float4*)&Bs[k][tn * 4];
            float a[4] = {a4.x, a4.y, a4.z, a4.w};
            float b[4] = {b4.x, b4.y, b4.z, b4.w};
#pragma unroll
            for (int i = 0; i < 4; ++i)
#pragma unroll
                for (int j = 0; j < 4; ++j) acc[i][j] = fmaf(a[i], b[j], acc[i][j]);
        }
        __syncthreads();
    }

#pragma unroll
    for (int i = 0; i < 4; ++i) {
        const int m = m0 + tm * 4 + i;
        const float bim = (EPI == 0 && bias) ? bias[m] : 0.f;
#pragma unroll
        for (int j = 0; j < 4; ++j) {
            const int n = n0 + tn * 4 + j;
            const size_t idx = (size_t)blockIdx.z * sC + (size_t)m * ldc + n;
            if (EPI == 0) C[idx] = acc[i][j] + bim;
            else          ((u16*)C)[idx] = f2bf(acc[i][j] + (bias ? bias[n] : 0.f));
        }
    }
}

// ---------------- softmax over bf16 rows of 4096, in place ----------------
__global__ void __launch_bounds__(256) softmax_att_kernel(u16* __restrict__ P) {
    u16* r = P + (size_t)blockIdx.x * 4096;
    const int tid = threadIdx.x;
    __shared__ float red[4], red2[4];
    float v[16];
    {
        s16x8 h0 = *(const s16x8*)(r + tid * 16);
        s16x8 h1 = *(const s16x8*)(r + tid * 16 + 8);
#pragma unroll
        for (int i = 0; i < 8; ++i) { v[i] = bf2f((u16)h0[i]); v[8 + i] = bf2f((u16)h1[i]); }
    }
    float mx = v[0];
#pragma unroll
    for (int i = 1; i < 16; ++i) mx = fmaxf(mx, v[i]);
    for (int o = 32; o > 0; o >>= 1) mx = fmaxf(mx, __shfl_down(mx, o, 64));
    if ((tid & 63) == 0) red[tid >> 6] = mx;
    __syncthreads();
    mx = fmaxf(fmaxf(red[0], red[1]), fmaxf(red[2], red[3]));
    float s = 0.f;
#pragma unroll
    for (int i = 0; i < 16; ++i) { v[i] = __expf(v[i] - mx); s += v[i]; }
    for (int o = 32; o > 0; o >>= 1) s += __shfl_down(s, o, 64);
    if ((tid & 63) == 0) red2[tid >> 6] = s;
    __syncthreads();
    s = red2[0] + red2[1] + red2[2] + red2[3];
    const float inv = 1.f / s;
    u16 w[16];
#pragma unroll
    for (int i = 0; i < 16; ++i) w[i] = f2bf(v[i] * inv);
    *(s16x8*)(r + tid * 16)     = *(s16x8*)&w[0];
    *(s16x8*)(r + tid * 16 + 8) = *(s16x8*)&w[8];
}

// ---------------- softmax fp32 rows of 512 -> bf16 out ----------------
__global__ void __launch_bounds__(256) softmax_g_kernel(const float* __restrict__ G, u16* __restrict__ Gs) {
    const float* r = G + (size_t)blockIdx.x * 512;
    u16* o = Gs + (size_t)blockIdx.x * 512;
    const int tid = threadIdx.x;
    __shared__ float red[4], red2[4];
    float2 v = *(const float2*)(r + tid * 2);
    float mx = fmaxf(v.x, v.y);
    for (int off = 32; off > 0; off >>= 1) mx = fmaxf(mx, __shfl_down(mx, off, 64));
    if ((tid & 63) == 0) red[tid >> 6] = mx;
    __syncthreads();
    mx = fmaxf(fmaxf(red[0], red[1]), fmaxf(red[2], red[3]));
    float e0 = __expf(v.x - mx), e1 = __expf(v.y - mx);
    float s = e0 + e1;
    for (int off = 32; off > 0; off >>= 1) s += __shfl_down(s, off, 64);
    if ((tid & 63) == 0) red2[tid >> 6] = s;
    __syncthreads();
    s = red2[0] + red2[1] + red2[2] + red2[3];
    const float inv = 1.f / s;
    o[tid * 2] = f2bf(e0 * inv);
    o[tid * 2 + 1] = f2bf(e1 * inv);
}

extern "C" void kernel_launch(void* const* d_in, const int* in_sizes, int n_in,
                              void* d_out, int out_size, void* d_ws, size_t ws_size,
                              hipStream_t stream) {
    const float* x     = (const float*)d_in[0];
    const float* sa_w1 = (const float*)d_in[1];
    const float* sa_g1 = (const float*)d_in[2];
    const float* sa_b1 = (const float*)d_in[3];
    const float* sa_m1 = (const float*)d_in[4];
    const float* sa_v1 = (const float*)d_in[5];
    const float* q_w   = (const float*)d_in[6];
    const float* q_b   = (const float*)d_in[7];
    const float* k_w   = (const float*)d_in[8];
    const float* k_b   = (const float*)d_in[9];
    const float* v_w   = (const float*)d_in[10];
    const float* v_b   = (const float*)d_in[11];
    const float* alpha = (const float*)d_in[12];
    const float* sa_w2 = (const float*)d_in[13];
    const float* sa_g2 = (const float*)d_in[14];
    const float* sa_b2 = (const float*)d_in[15];
    const float* sa_m2 = (const float*)d_in[16];
    const float* sa_v2 = (const float*)d_in[17];
    const float* ca_w1 = (const float*)d_in[18];
    const float* ca_g1 = (const float*)d_in[19];
    const float* ca_b1 = (const float*)d_in[20];
    const float* ca_m1 = (const float*)d_in[21];
    const float* ca_v1 = (const float*)d_in[22];
    const float* beta  = (const float*)d_in[23];
    const float* ca_w2 = (const float*)d_in[24];
    const float* ca_g2 = (const float*)d_in[25];
    const float* ca_b2 = (const float*)d_in[26];
    const float* ca_m2 = (const float*)d_in[27];
    const float* ca_v2 = (const float*)d_in[28];

    float* out = (float*)d_out;

    // ---- workspace layout (~160 MB, proven budget 181 MB) ----
    char* wsb = (char*)d_ws;
    float* S1f = (float*)wsb;                 wsb += 8388608ull * 4;   // [4][512][4096]
    float* C1f = (float*)wsb;                 wsb += 8388608ull * 4;
    float* G   = (float*)wsb;                 wsb += 1048576ull * 4;   // [4][512][512]
    u16* Tcl   = (u16*)wsb;                   wsb += 8921088ull * 2;   // [4][66][66][512]
    u16* CLB   = (u16*)wsb;                   wsb += 8388608ull * 2;   // [4][4096][512]
    u16* Wb    = (u16*)wsb;                   wsb += 2359296ull * 2;   // [9][512][512]
    u16* VWb   = (u16*)wsb;                   wsb += 262144ull * 2;    // [512][512]
    u16* Vb    = (u16*)wsb;                   wsb += 8388608ull * 2;   // [4][512][4096] (reused as C1b)
    u16* ATT   = (u16*)wsb;                   wsb += 16777216ull * 2;  // [4096][4096]
    u16* Gsb   = (u16*)wsb;                   wsb += 1048576ull * 2;   // [4][512][512]
    u16* Qt    = (u16*)wsb;                   wsb += 1048576ull * 2;   // [4][4096][64]
    u16* Kt    = (u16*)wsb;                   wsb += 1048576ull * 2;   // [4][4096][64]
    u16* C1b   = Vb;   // alias: Vb dead after spatial branch

    const long IMG = 512L * 4096;
    dim3 cgrid(32, 4, 4);
    dim3 tgrid(8, 64, 4);

    // 0. zero padded channel-last buffer
    zero_kernel<<<4357, 256, 0, stream>>>((uint4*)Tcl, 1115136);

    // 1. conv1 both branches from x
    tcl_kernel<<<tgrid, 256, 0, stream>>>(x, Tcl, 1);
    wpack_kernel<<<9216, 256, 0, stream>>>(sa_w1, Wb);
    conv_mfma_kernel<0><<<cgrid, 256, 0, stream>>>(Tcl, Wb, sa_g1, sa_b1, sa_m1, sa_v1, S1f);
    wpack_kernel<<<9216, 256, 0, stream>>>(ca_w1, Wb);
    conv_mfma_kernel<0><<<cgrid, 256, 0, stream>>>(Tcl, Wb, ca_g1, ca_b1, ca_m1, ca_v1, C1f);

    // 2. Qt/Kt: [4][4096 s][64 o] bf16, bias over o   (Qt = S1^T q_w^T + q_b)
    gemm_kernel<1, 1, 3><<<dim3(1, 64, 4), 256, 0, stream>>>(
        S1f, 4096, IMG, q_w, 512, 0, (float*)Qt, 64, 262144, 512, q_b);
    gemm_kernel<1, 1, 3><<<dim3(1, 64, 4), 256, 0, stream>>>(
        S1f, 4096, IMG, k_w, 512, 0, (float*)Kt, 64, 262144, 512, k_b);

    // 3. v projection (bf16 NT from compact channel-last)
    cvtb_kernel<<<1024, 256, 0, stream>>>(v_w, VWb, 262144);
    tcl_kernel<<<tgrid, 256, 0, stream>>>(S1f, CLB, 0);
    mfma_nt_kernel<0><<<dim3(32, 4, 4), 256, 0, stream>>>(
        VWb, 512, 0, CLB, 512, 2097152, Vb, 4096, 2097152, 512, v_b, nullptr);

    // 4. spatial attention per batch: ATT = Qt Kt^T (bf16 MFMA, K=64); softmax; S1 += alpha V ATT^T
    for (int b = 0; b < 4; ++b) {
        mfma_nt_kernel<0><<<dim3(32, 32, 1), 256, 0, stream>>>(
            Qt + b * 262144, 64, 0, Kt + b * 262144, 64, 0, ATT, 4096, 0, 64, nullptr, nullptr);
        softmax_att_kernel<<<4096, 256, 0, stream>>>(ATT);
        mfma_nt_kernel<1><<<dim3(32, 4, 1), 256, 0, stream>>>(
            Vb + b * 2097152, 4096, 0, ATT, 4096, 0, S1f + b * IMG, 4096, 0, 4096, nullptr, alpha);
    }

    // 5. sa_out = BNReLU(conv(s1, sa_w2)) -> d_out
    tcl_kernel<<<tgrid, 256, 0, stream>>>(S1f, Tcl, 1);
    wpack_kernel<<<9216, 256, 0, stream>>>(sa_w2, Wb);
    conv_mfma_kernel<0><<<cgrid, 256, 0, stream>>>(Tcl, Wb, sa_g2, sa_b2, sa_m2, sa_v2, out);

    // 6. channel attention: G = cf cf^T (bf16 MFMA); softmax; c1 += beta (G_sm cf)
    cvtb_kernel<<<32768, 256, 0, stream>>>(C1f, C1b, 8388608);
    mfma_nt_kernel<2><<<dim3(4, 4, 4), 256, 0, stream>>>(
        C1b, 4096, 2097152, C1b, 4096, 2097152, G, 512, 262144, 4096, nullptr, nullptr);
    softmax_g_kernel<<<2048, 256, 0, stream>>>(G, Gsb);
    tcl_kernel<<<tgrid, 256, 0, stream>>>(C1f, CLB, 0);
    mfma_nt_kernel<1><<<dim3(32, 4, 4), 256, 0, stream>>>(
        Gsb, 512, 262144, CLB, 512, 2097152, C1f, 4096, IMG, 512, nullptr, beta);

    // 7. out += BNReLU(conv(c1, ca_w2))
    tcl_kernel<<<tgrid, 256, 0, stream>>>(C1f, Tcl, 1);
    wpack_kernel<<<9216, 256, 0, stream>>>(ca_w2, Wb);
    conv_mfma_kernel<2><<<cgrid, 256, 0, stream>>>(Tcl, Wb, ca_g2, ca_b2, ca_m2, ca_v2, out);
}

// Round 10
// 1222.061 us; speedup vs baseline: 5.0999x; 1.0554x over previous
//
#include <hip/hip_runtime.h>
#include <hip/hip_bf16.h>

// B=4, C=512, H=W=64, S=4096, CI=64.  All heavy GEMMs bf16 MFMA with LDS XOR swizzle.
#define EPS_ 1e-5f

typedef __attribute__((ext_vector_type(4))) float f32x4;
typedef __attribute__((ext_vector_type(8))) short s16x8;
typedef unsigned short u16;

__device__ __forceinline__ float bf2f(u16 u) { return __uint_as_float(((unsigned)u) << 16); }
__device__ __forceinline__ u16 f2bf(float f) { __hip_bfloat16 h = __float2bfloat16(f); return *(u16*)&h; }

typedef __attribute__((address_space(3))) unsigned int lds_u32;
typedef const __attribute__((address_space(1))) unsigned int glb_u32;
__device__ __forceinline__ void gload16(const u16* g, u16* l) {
    __builtin_amdgcn_global_load_lds((glb_u32*)g, (lds_u32*)l, 16, 0, 0);
}

// ---------------- zero fill (uint4) ----------------
__global__ void __launch_bounds__(256) zero_kernel(uint4* __restrict__ p, int n) {
    int i = blockIdx.x * 256 + threadIdx.x;
    if (i < n) p[i] = make_uint4(0, 0, 0, 0);
}

// ------------- weight pack OIHW fp32 -> [9][512 o][512 ci] bf16 -------------
__global__ void __launch_bounds__(256) wpack_kernel(const float* __restrict__ w, u16* __restrict__ wp) {
    int gid = blockIdx.x * 256 + threadIdx.x;
    if (gid >= 9 * 512 * 512) return;
    int tap = gid >> 18, rem = gid & 262143;
    int o = rem >> 9, c = rem & 511;
    wp[gid] = f2bf(w[(o * 512 + c) * 9 + tap]);
}

// ------------- fp32 [n] -> bf16 [n] -------------
__global__ void __launch_bounds__(256) cvtb_kernel(const float* __restrict__ a, u16* __restrict__ o, int n) {
    int i = blockIdx.x * 256 + threadIdx.x;
    if (i < n) o[i] = f2bf(a[i]);
}

// ------------- concat q_b|k_b -> 128 floats -------------
__global__ void qkbias_kernel(const float* __restrict__ qb, const float* __restrict__ kb,
                              float* __restrict__ o) {
    int i = threadIdx.x;
    o[i] = (i < 64) ? qb[i] : kb[i - 64];
}

// ------------- NCHW fp32 -> channel-last bf16 (padded [66][66][512] or compact [4096][512]) -------------
__global__ void __launch_bounds__(256) tcl_kernel(const float* __restrict__ X, u16* __restrict__ out, int padded) {
    __shared__ float T[64][65];
    const int b = blockIdx.z, y = blockIdx.y, c0 = blockIdx.x * 64;
    const int tid = threadIdx.x;
    const int rr = tid >> 2, q = (tid & 3) * 16;
    const float* src = X + (((size_t)(b * 512 + c0 + rr) * 64 + y) * 64) + q;
#pragma unroll
    for (int i = 0; i < 4; ++i) {
        float4 f = *(const float4*)(src + i * 4);
        T[rr][q + i * 4 + 0] = f.x; T[rr][q + i * 4 + 1] = f.y;
        T[rr][q + i * 4 + 2] = f.z; T[rr][q + i * 4 + 3] = f.w;
    }
    __syncthreads();
    u16 v[16];
#pragma unroll
    for (int i = 0; i < 16; ++i) v[i] = f2bf(T[q + i][rr]);
    u16* dst = padded ? out + ((size_t)((b * 66 + y + 1) * 66 + rr + 1)) * 512 + c0 + q
                      : out + ((size_t)(b * 4096 + y * 64 + rr)) * 512 + c0 + q;
    *(s16x8*)dst       = *(s16x8*)&v[0];
    *(s16x8*)(dst + 8) = *(s16x8*)&v[8];
}

// ---------------- conv3x3 bf16 MFMA (implicit GEMM, XOR-swizzled LDS) ----------------
template <int MODE>   // 0: Y = bnrelu; 2: Y += bnrelu
__global__ void __launch_bounds__(256) conv_mfma_kernel(
        const u16* __restrict__ Tcl, const u16* __restrict__ Wb,
        const float* __restrict__ gg, const float* __restrict__ bb,
        const float* __restrict__ mn, const float* __restrict__ vr,
        float* __restrict__ Y) {
    __shared__ __align__(16) u16 Ash[4096];   // [128 m][32 k], col ^ ((row>>1)&3)<<3
    __shared__ __align__(16) u16 Bsh[4096];
    const int tid = threadIdx.x, lane = tid & 63, wid = tid >> 6;
    const int wm = wid >> 1, wn = wid & 1;
    const int b = blockIdx.z, m0 = blockIdx.y * 128, s0 = blockIdx.x * 128;
    const int y0 = s0 >> 6;

    const int off0 = wid * 1024 + lane * 16;
    const int row0 = off0 >> 6;
    // pre-swizzled source k-offset: phys slot receives logical col ^ ((row&..bits1-2)<<3)
    const int kb0 = (((off0 & 63) >> 1)) ^ (((lane >> 3) & 3) << 3);
    const int x_im = row0 & 63;
    const size_t aoff0 = (size_t)(m0 + row0) * 512 + kb0;
    const size_t aoff1 = aoff0 + (size_t)64 * 512;
    const size_t bbase0 = ((size_t)(b * 66 + y0 + 1) * 66 + x_im + 1) * 512 + kb0;
    const size_t bbase1 = ((size_t)(b * 66 + y0 + 2) * 66 + x_im + 1) * 512 + kb0;
    u16* ldsA0 = Ash + wid * 512; u16* ldsA1 = ldsA0 + 2048;
    u16* ldsB0 = Bsh + wid * 512; u16* ldsB1 = ldsB0 + 2048;

    f32x4 acc[4][4];
#pragma unroll
    for (int i = 0; i < 4; ++i)
#pragma unroll
        for (int j = 0; j < 4; ++j) acc[i][j] = (f32x4){0.f, 0.f, 0.f, 0.f};

    const int ra = wm * 64 + (lane & 15);
    const int rb = wn * 64 + (lane & 15);
    const int kq = ((lane >> 4) * 8) ^ (((lane >> 1) & 3) << 3);   // swizzled read col

    for (int tap = 0; tap < 9; ++tap) {
        const u16* At = Wb + (size_t)tap * 262144;
        const long bshift = (long)((tap / 3 - 1) * 66 + (tap % 3 - 1)) * 512;
        const u16* Bt0 = Tcl + bbase0 + bshift;
        const u16* Bt1 = Tcl + bbase1 + bshift;
        for (int k0 = 0; k0 < 512; k0 += 32) {
            gload16(At + aoff0 + k0, ldsA0);
            gload16(At + aoff1 + k0, ldsA1);
            gload16(Bt0 + k0, ldsB0);
            gload16(Bt1 + k0, ldsB1);
            __syncthreads();
            s16x8 a[4], bf[4];
#pragma unroll
            for (int i = 0; i < 4; ++i) a[i]  = *(const s16x8*)&Ash[(ra + i * 16) * 32 + kq];
#pragma unroll
            for (int j = 0; j < 4; ++j) bf[j] = *(const s16x8*)&Bsh[(rb + j * 16) * 32 + kq];
#pragma unroll
            for (int i = 0; i < 4; ++i)
#pragma unroll
                for (int j = 0; j < 4; ++j)
                    acc[i][j] = __builtin_amdgcn_mfma_f32_16x16x32_bf16(a[i], bf[j], acc[i][j], 0, 0, 0);
            __syncthreads();
        }
    }

#pragma unroll
    for (int i = 0; i < 4; ++i) {
#pragma unroll
        for (int r = 0; r < 4; ++r) {
            const int c = m0 + wm * 64 + i * 16 + (lane >> 4) * 4 + r;
            const float sc = gg[c] * rsqrtf(vr[c] + EPS_);
            const float bn = bb[c] - mn[c] * sc;
            const size_t rowi = ((size_t)(b * 512 + c)) * 4096;
#pragma unroll
            for (int j = 0; j < 4; ++j) {
                const int s = s0 + wn * 64 + j * 16 + (lane & 15);
                const float v = fmaxf(acc[i][j][r] * sc + bn, 0.f);
                if (MODE == 0) Y[rowi + s] = v;
                else           Y[rowi + s] += v;
            }
        }
    }
}

// ---------------- generic bf16 MFMA NT GEMM: D[m][n] = sum_k A[m][k] B[n][k] ----------------
// EPI 0: (bf16*)C = acc + bias[m];  EPI 1: (float*)C += scalar*acc;
// EPI 2: (float*)C = acc;           EPI 3: (bf16*)C = acc + bias[n]
template <int EPI>
__global__ void __launch_bounds__(256) mfma_nt_kernel(
        const u16* __restrict__ A, int lda, long sA,
        const u16* __restrict__ Bm, int ldb, long sB,
        void* __restrict__ C, int ldc, long sC,
        int K, const float* __restrict__ bias, const float* __restrict__ scalar_p) {
    __shared__ __align__(16) u16 Ash[4096];
    __shared__ __align__(16) u16 Bsh[4096];
    const int tid = threadIdx.x, lane = tid & 63, wid = tid >> 6;
    const int wm = wid >> 1, wn = wid & 1;
    const int m0 = blockIdx.y * 128, n0 = blockIdx.x * 128;
    const u16* Ab = A + (size_t)blockIdx.z * sA;
    const u16* Bb = Bm + (size_t)blockIdx.z * sB;

    const int off0 = wid * 1024 + lane * 16;
    const int row0 = off0 >> 6;
    const int kb0 = (((off0 & 63) >> 1)) ^ (((lane >> 3) & 3) << 3);
    const size_t aoff0 = (size_t)(m0 + row0) * lda + kb0;
    const size_t aoff1 = aoff0 + (size_t)64 * lda;
    const size_t boff0 = (size_t)(n0 + row0) * ldb + kb0;
    const size_t boff1 = boff0 + (size_t)64 * ldb;
    u16* ldsA0 = Ash + wid * 512; u16* ldsA1 = ldsA0 + 2048;
    u16* ldsB0 = Bsh + wid * 512; u16* ldsB1 = ldsB0 + 2048;

    f32x4 acc[4][4];
#pragma unroll
    for (int i = 0; i < 4; ++i)
#pragma unroll
        for (int j = 0; j < 4; ++j) acc[i][j] = (f32x4){0.f, 0.f, 0.f, 0.f};

    const int ra = wm * 64 + (lane & 15);
    const int rb = wn * 64 + (lane & 15);
    const int kq = ((lane >> 4) * 8) ^ (((lane >> 1) & 3) << 3);

    for (int k0 = 0; k0 < K; k0 += 32) {
        gload16(Ab + aoff0 + k0, ldsA0);
        gload16(Ab + aoff1 + k0, ldsA1);
        gload16(Bb + boff0 + k0, ldsB0);
        gload16(Bb + boff1 + k0, ldsB1);
        __syncthreads();
        s16x8 a[4], bf[4];
#pragma unroll
        for (int i = 0; i < 4; ++i) a[i]  = *(const s16x8*)&Ash[(ra + i * 16) * 32 + kq];
#pragma unroll
        for (int j = 0; j < 4; ++j) bf[j] = *(const s16x8*)&Bsh[(rb + j * 16) * 32 + kq];
#pragma unroll
        for (int i = 0; i < 4; ++i)
#pragma unroll
            for (int j = 0; j < 4; ++j)
                acc[i][j] = __builtin_amdgcn_mfma_f32_16x16x32_bf16(a[i], bf[j], acc[i][j], 0, 0, 0);
        __syncthreads();
    }

#pragma unroll
    for (int i = 0; i < 4; ++i) {
#pragma unroll
        for (int r = 0; r < 4; ++r) {
            const int m = m0 + wm * 64 + i * 16 + (lane >> 4) * 4 + r;
            const float bim = (EPI == 0 && bias) ? bias[m] : 0.f;
#pragma unroll
            for (int j = 0; j < 4; ++j) {
                const int n = n0 + wn * 64 + j * 16 + (lane & 15);
                const size_t idx = (size_t)blockIdx.z * sC + (size_t)m * ldc + n;
                if (EPI == 0)      ((u16*)C)[idx] = f2bf(acc[i][j][r] + bim);
                else if (EPI == 1) ((float*)C)[idx] += scalar_p[0] * acc[i][j][r];
                else if (EPI == 2) ((float*)C)[idx] = acc[i][j][r];
                else               ((u16*)C)[idx] = f2bf(acc[i][j][r] + (bias ? bias[n] : 0.f));
            }
        }
    }
}

// ---------------- softmax over bf16 rows of 4096, in place ----------------
__global__ void __launch_bounds__(256) softmax_att_kernel(u16* __restrict__ P) {
    u16* r = P + (size_t)blockIdx.x * 4096;
    const int tid = threadIdx.x;
    __shared__ float red[4], red2[4];
    float v[16];
    {
        s16x8 h0 = *(const s16x8*)(r + tid * 16);
        s16x8 h1 = *(const s16x8*)(r + tid * 16 + 8);
#pragma unroll
        for (int i = 0; i < 8; ++i) { v[i] = bf2f((u16)h0[i]); v[8 + i] = bf2f((u16)h1[i]); }
    }
    float mx = v[0];
#pragma unroll
    for (int i = 1; i < 16; ++i) mx = fmaxf(mx, v[i]);
    for (int o = 32; o > 0; o >>= 1) mx = fmaxf(mx, __shfl_down(mx, o, 64));
    if ((tid & 63) == 0) red[tid >> 6] = mx;
    __syncthreads();
    mx = fmaxf(fmaxf(red[0], red[1]), fmaxf(red[2], red[3]));
    float s = 0.f;
#pragma unroll
    for (int i = 0; i < 16; ++i) { v[i] = __expf(v[i] - mx); s += v[i]; }
    for (int o = 32; o > 0; o >>= 1) s += __shfl_down(s, o, 64);
    if ((tid & 63) == 0) red2[tid >> 6] = s;
    __syncthreads();
    s = red2[0] + red2[1] + red2[2] + red2[3];
    const float inv = 1.f / s;
    u16 w[16];
#pragma unroll
    for (int i = 0; i < 16; ++i) w[i] = f2bf(v[i] * inv);
    *(s16x8*)(r + tid * 16)     = *(s16x8*)&w[0];
    *(s16x8*)(r + tid * 16 + 8) = *(s16x8*)&w[8];
}

// ---------------- softmax fp32 rows of 512 -> bf16 out ----------------
__global__ void __launch_bounds__(256) softmax_g_kernel(const float* __restrict__ G, u16* __restrict__ Gs) {
    const float* r = G + (size_t)blockIdx.x * 512;
    u16* o = Gs + (size_t)blockIdx.x * 512;
    const int tid = threadIdx.x;
    __shared__ float red[4], red2[4];
    float2 v = *(const float2*)(r + tid * 2);
    float mx = fmaxf(v.x, v.y);
    for (int off = 32; off > 0; off >>= 1) mx = fmaxf(mx, __shfl_down(mx, off, 64));
    if ((tid & 63) == 0) red[tid >> 6] = mx;
    __syncthreads();
    mx = fmaxf(fmaxf(red[0], red[1]), fmaxf(red[2], red[3]));
    float e0 = __expf(v.x - mx), e1 = __expf(v.y - mx);
    float s = e0 + e1;
    for (int off = 32; off > 0; off >>= 1) s += __shfl_down(s, off, 64);
    if ((tid & 63) == 0) red2[tid >> 6] = s;
    __syncthreads();
    s = red2[0] + red2[1] + red2[2] + red2[3];
    const float inv = 1.f / s;
    o[tid * 2] = f2bf(e0 * inv);
    o[tid * 2 + 1] = f2bf(e1 * inv);
}

extern "C" void kernel_launch(void* const* d_in, const int* in_sizes, int n_in,
                              void* d_out, int out_size, void* d_ws, size_t ws_size,
                              hipStream_t stream) {
    const float* x     = (const float*)d_in[0];
    const float* sa_w1 = (const float*)d_in[1];
    const float* sa_g1 = (const float*)d_in[2];
    const float* sa_b1 = (const float*)d_in[3];
    const float* sa_m1 = (const float*)d_in[4];
    const float* sa_v1 = (const float*)d_in[5];
    const float* q_w   = (const float*)d_in[6];
    const float* q_b   = (const float*)d_in[7];
    const float* k_w   = (const float*)d_in[8];
    const float* k_b   = (const float*)d_in[9];
    const float* v_w   = (const float*)d_in[10];
    const float* v_b   = (const float*)d_in[11];
    const float* alpha = (const float*)d_in[12];
    const float* sa_w2 = (const float*)d_in[13];
    const float* sa_g2 = (const float*)d_in[14];
    const float* sa_b2 = (const float*)d_in[15];
    const float* sa_m2 = (const float*)d_in[16];
    const float* sa_v2 = (const float*)d_in[17];
    const float* ca_w1 = (const float*)d_in[18];
    const float* ca_g1 = (const float*)d_in[19];
    const float* ca_b1 = (const float*)d_in[20];
    const float* ca_m1 = (const float*)d_in[21];
    const float* ca_v1 = (const float*)d_in[22];
    const float* beta  = (const float*)d_in[23];
    const float* ca_w2 = (const float*)d_in[24];
    const float* ca_g2 = (const float*)d_in[25];
    const float* ca_b2 = (const float*)d_in[26];
    const float* ca_m2 = (const float*)d_in[27];
    const float* ca_v2 = (const float*)d_in[28];

    float* out = (float*)d_out;

    // ---- workspace layout (~160 MB) ----
    char* wsb = (char*)d_ws;
    float* S1f = (float*)wsb;                 wsb += 8388608ull * 4;   // [4][512][4096]
    float* C1f = (float*)wsb;                 wsb += 8388608ull * 4;
    float* G   = (float*)wsb;                 wsb += 1048576ull * 4;   // [4][512][512]
    float* QKB = (float*)wsb;                 wsb += 128 * 4;          // q_b|k_b
    u16* Tcl   = (u16*)wsb;                   wsb += 8921088ull * 2;   // [4][66][66][512]
    u16* CLB   = (u16*)wsb;                   wsb += 8388608ull * 2;   // [4][4096][512]
    u16* Wb    = (u16*)wsb;                   wsb += 2359296ull * 2;   // [9][512][512]
    u16* VWb   = (u16*)wsb;                   wsb += 262144ull * 2;    // [512][512]
    u16* QKw   = (u16*)wsb;                   wsb += 65536ull * 2;     // [128][512] q_w|k_w
    u16* Vb    = (u16*)wsb;                   wsb += 8388608ull * 2;   // [4][512][4096] (reused as C1b)
    u16* ATT   = (u16*)wsb;                   wsb += 16777216ull * 2;  // [4096][4096]
    u16* Gsb   = (u16*)wsb;                   wsb += 1048576ull * 2;   // [4][512][512]
    u16* QKt   = (u16*)wsb;                   wsb += 2097152ull * 2;   // [4][4096][128]  Q|K
    u16* C1b   = Vb;   // alias: Vb dead after spatial branch

    const long IMG = 512L * 4096;
    dim3 cgrid(32, 4, 4);
    dim3 tgrid(8, 64, 4);

    // 0. zero padded channel-last buffer
    zero_kernel<<<4357, 256, 0, stream>>>((uint4*)Tcl, 1115136);

    // 1. conv1 both branches from x
    tcl_kernel<<<tgrid, 256, 0, stream>>>(x, Tcl, 1);
    wpack_kernel<<<9216, 256, 0, stream>>>(sa_w1, Wb);
    conv_mfma_kernel<0><<<cgrid, 256, 0, stream>>>(Tcl, Wb, sa_g1, sa_b1, sa_m1, sa_v1, S1f);
    wpack_kernel<<<9216, 256, 0, stream>>>(ca_w1, Wb);
    conv_mfma_kernel<0><<<cgrid, 256, 0, stream>>>(Tcl, Wb, ca_g1, ca_b1, ca_m1, ca_v1, C1f);

    // 2. small weight packs
    cvtb_kernel<<<1024, 256, 0, stream>>>(v_w, VWb, 262144);
    cvtb_kernel<<<128, 256, 0, stream>>>(q_w, QKw, 32768);
    cvtb_kernel<<<128, 256, 0, stream>>>(k_w, QKw + 32768, 32768);
    qkbias_kernel<<<1, 128, 0, stream>>>(q_b, k_b, QKB);

    // 3. channel-last S1 -> QKt (fused q/k proj, bf16 MFMA) and V proj
    tcl_kernel<<<tgrid, 256, 0, stream>>>(S1f, CLB, 0);
    mfma_nt_kernel<3><<<dim3(1, 32, 4), 256, 0, stream>>>(
        CLB, 512, 2097152, QKw, 512, 0, QKt, 128, 524288, 512, QKB, nullptr);
    mfma_nt_kernel<0><<<dim3(32, 4, 4), 256, 0, stream>>>(
        VWb, 512, 0, CLB, 512, 2097152, Vb, 4096, 2097152, 512, v_b, nullptr);

    // 4. spatial attention per batch: ATT = Q K^T (K=64); softmax; S1 += alpha V ATT^T
    for (int b = 0; b < 4; ++b) {
        mfma_nt_kernel<0><<<dim3(32, 32, 1), 256, 0, stream>>>(
            QKt + b * 524288, 128, 0, QKt + b * 524288 + 64, 128, 0, ATT, 4096, 0, 64, nullptr, nullptr);
        softmax_att_kernel<<<4096, 256, 0, stream>>>(ATT);
        mfma_nt_kernel<1><<<dim3(32, 4, 1), 256, 0, stream>>>(
            Vb + b * 2097152, 4096, 0, ATT, 4096, 0, S1f + b * IMG, 4096, 0, 4096, nullptr, alpha);
    }

    // 5. sa_out = BNReLU(conv(s1, sa_w2)) -> d_out
    tcl_kernel<<<tgrid, 256, 0, stream>>>(S1f, Tcl, 1);
    wpack_kernel<<<9216, 256, 0, stream>>>(sa_w2, Wb);
    conv_mfma_kernel<0><<<cgrid, 256, 0, stream>>>(Tcl, Wb, sa_g2, sa_b2, sa_m2, sa_v2, out);

    // 6. channel attention: G = cf cf^T; softmax; c1 += beta (G_sm cf)
    cvtb_kernel<<<32768, 256, 0, stream>>>(C1f, C1b, 8388608);
    mfma_nt_kernel<2><<<dim3(4, 4, 4), 256, 0, stream>>>(
        C1b, 4096, 2097152, C1b, 4096, 2097152, G, 512, 262144, 4096, nullptr, nullptr);
    softmax_g_kernel<<<2048, 256, 0, stream>>>(G, Gsb);
    tcl_kernel<<<tgrid, 256, 0, stream>>>(C1f, CLB, 0);
    mfma_nt_kernel<1><<<dim3(32, 4, 4), 256, 0, stream>>>(
        Gsb, 512, 262144, CLB, 512, 2097152, C1f, 4096, IMG, 512, nullptr, beta);

    // 7. out += BNReLU(conv(c1, ca_w2))
    tcl_kernel<<<tgrid, 256, 0, stream>>>(C1f, Tcl, 1);
    wpack_kernel<<<9216, 256, 0, stream>>>(ca_w2, Wb);
    conv_mfma_kernel<2><<<cgrid, 256, 0, stream>>>(Tcl, Wb, ca_g2, ca_b2, ca_m2, ca_v2, out);
}